// Round 6
// baseline (340.306 us; speedup 1.0000x reference)
//
#include <hip/hip_runtime.h>
#include <math.h>

// Problem constants (fixed by setup_inputs)
#define NP 8192      // pred vertices
#define NG 12000     // gt vertices
#define NFP 16384    // pred faces
#define NFG 24000    // gt faces
#define EPSF 1e-6f

// uniform grid for NN: 16^3 cells over [0,1]^3, ~3 gt / ~2 pred per cell
#define GR 16
#define NC (GR*GR*GR)        // 4096
#define HCELL 0.0625f        // 1/16, exact power of two
#define QL 16                // lanes cooperating per NN query

// ---- workspace layout (bytes) ----
static constexpr size_t OFF_STARTP = 0;        // 4096 u32 cell start (pred)
static constexpr size_t OFF_CURP   = 16384;    // 4096 u32 cursor -> end after scatter
static constexpr size_t OFF_STARTG = 32768;    // 4096 u32 cell start (gt)
static constexpr size_t OFF_CURG   = 49152;    // 4096 u32 cursor -> end
static constexpr size_t OFF_SORTP  = 65536;    // 8192  float4 (x,y,z,idx-as-float-bits)
static constexpr size_t OFF_SORTG  = 196608;   // 12000 float4
static constexpr size_t OFF_GTN    = 388608;   // NG*3 f32 gt normal accum (raw)
static constexpr size_t OFF_PNN    = 532608;   // NP*3 f32 pred normal accum
static constexpr size_t OFF_NSUM   = 630912;   // NP*3 f32 laplacian neighbor sum
static constexpr size_t OFF_DEG    = 729216;   // NP   f32 laplacian degree
static constexpr size_t OFF_SCAL   = 761984;   // 7 f32 [sum_row,sum_col,pc,SX,SY,sse,lap]
static constexpr size_t OFF_TICKET = 762012;   // 1 u32
#define N_ZERO 93352   // floats from OFF_GTN through ticket (contiguous)

__device__ __forceinline__ int cell_of(float x) {
    int c = (int)(x * (float)GR);
    return min(max(c, 0), GR - 1);
}

// histogram + exclusive scan of one point set into start/cur (1024-thread block)
__device__ __forceinline__ void hist_scan(const float* __restrict__ pts, int n,
                                          unsigned* __restrict__ start,
                                          unsigned* __restrict__ cur,
                                          unsigned* h, unsigned* ps) {
    int t = threadIdx.x;
    for (int i = t; i < NC; i += 1024) h[i] = 0u;
    __syncthreads();
    for (int i = t; i < n; i += 1024) {
        int c = (cell_of(pts[3*i+2]) * GR + cell_of(pts[3*i+1])) * GR + cell_of(pts[3*i]);
        atomicAdd(&h[c], 1u);
    }
    __syncthreads();
    unsigned a0 = h[4*t], a1 = h[4*t+1], a2 = h[4*t+2], a3 = h[4*t+3];
    unsigned tsum = a0 + a1 + a2 + a3;
    ps[t] = tsum; __syncthreads();
    for (int off = 1; off < 1024; off <<= 1) {
        unsigned v = (t >= off) ? ps[t - off] : 0u;
        __syncthreads();
        ps[t] += v;
        __syncthreads();
    }
    unsigned ex = ps[t] - tsum;
    h[4*t] = ex; h[4*t+1] = ex + a0; h[4*t+2] = ex + a0 + a1; h[4*t+3] = ex + a0 + a1 + a2;
    __syncthreads();
    for (int i = t; i < NC; i += 1024) { start[i] = h[i]; cur[i] = h[i]; }
}

// Dispatch 1: block 0 = pred histogram+scan, block 1 = gt histogram+scan,
//             blocks >=2 = zero the accumulator region.
__global__ __launch_bounds__(1024) void build_kernel(const float* __restrict__ pred,
                                                     const float* __restrict__ gt,
                                                     unsigned* __restrict__ startP,
                                                     unsigned* __restrict__ curP,
                                                     unsigned* __restrict__ startG,
                                                     unsigned* __restrict__ curG,
                                                     float* __restrict__ zero) {
    __shared__ unsigned h[NC];
    __shared__ unsigned ps[1024];
    if (blockIdx.x == 0) {
        hist_scan(pred, NP, startP, curP, h, ps);
    } else if (blockIdx.x == 1) {
        hist_scan(gt, NG, startG, curG, h, ps);
    } else {
        int i = (blockIdx.x - 2) * 1024 + threadIdx.x;
        if (i < N_ZERO) zero[i] = 0.0f;
    }
}

// Dispatch 2: scatter points into cell-sorted arrays + face-normal/laplacian scatter.
#define SCAT_P_BLOCKS 32                        // 8192/256
#define SCAT_G_BLOCKS 47                        // ceil(12000/256)
#define SCAT_BLOCKS (SCAT_P_BLOCKS + SCAT_G_BLOCKS)
#define FACE_BLOCKS ((NFG + NFP + 255) / 256)   // 158
__global__ __launch_bounds__(256) void scatter_faces_kernel(const float* __restrict__ pred,
                                                            const int* __restrict__ pf,
                                                            const float* __restrict__ gt,
                                                            const int* __restrict__ gf,
                                                            unsigned* __restrict__ curP,
                                                            unsigned* __restrict__ curG,
                                                            float4* __restrict__ sortP,
                                                            float4* __restrict__ sortG,
                                                            float* __restrict__ gtn,
                                                            float* __restrict__ pnn,
                                                            float* __restrict__ nsum,
                                                            float* __restrict__ deg) {
    int b = blockIdx.x;
    if (b < SCAT_P_BLOCKS) {
        int i = b * 256 + threadIdx.x;            // < 8192 always
        float x = pred[3*i], y = pred[3*i+1], z = pred[3*i+2];
        int c = (cell_of(z) * GR + cell_of(y)) * GR + cell_of(x);
        unsigned pos = atomicAdd(&curP[c], 1u);
        sortP[pos] = make_float4(x, y, z, __int_as_float(i));
    } else if (b < SCAT_BLOCKS) {
        int i = (b - SCAT_P_BLOCKS) * 256 + threadIdx.x;
        if (i < NG) {
            float x = gt[3*i], y = gt[3*i+1], z = gt[3*i+2];
            int c = (cell_of(z) * GR + cell_of(y)) * GR + cell_of(x);
            unsigned pos = atomicAdd(&curG[c], 1u);
            sortG[pos] = make_float4(x, y, z, __int_as_float(i));
        }
    } else {
        int t = (b - SCAT_BLOCKS) * 256 + threadIdx.x;
        if (t < NFG) {
            int i0 = gf[3*t], i1 = gf[3*t+1], i2 = gf[3*t+2];
            float ax = gt[3*i0], ay = gt[3*i0+1], az = gt[3*i0+2];
            float bx = gt[3*i1], by = gt[3*i1+1], bz = gt[3*i1+2];
            float cx = gt[3*i2], cy = gt[3*i2+1], cz = gt[3*i2+2];
            float ux = bx-ax, uy = by-ay, uz = bz-az;
            float wx = cx-ax, wy = cy-ay, wz = cz-az;
            float nx = uy*wz - uz*wy, ny = uz*wx - ux*wz, nz = ux*wy - uy*wx;
            atomicAdd(&gtn[3*i0+0], nx); atomicAdd(&gtn[3*i0+1], ny); atomicAdd(&gtn[3*i0+2], nz);
            atomicAdd(&gtn[3*i1+0], nx); atomicAdd(&gtn[3*i1+1], ny); atomicAdd(&gtn[3*i1+2], nz);
            atomicAdd(&gtn[3*i2+0], nx); atomicAdd(&gtn[3*i2+1], ny); atomicAdd(&gtn[3*i2+2], nz);
        } else if (t < NFG + NFP) {
            int u = t - NFG;
            int i0 = pf[3*u], i1 = pf[3*u+1], i2 = pf[3*u+2];
            float ax = pred[3*i0], ay = pred[3*i0+1], az = pred[3*i0+2];
            float bx = pred[3*i1], by = pred[3*i1+1], bz = pred[3*i1+2];
            float cx = pred[3*i2], cy = pred[3*i2+1], cz = pred[3*i2+2];
            float ux = bx-ax, uy = by-ay, uz = bz-az;
            float wx = cx-ax, wy = cy-ay, wz = cz-az;
            float nx = uy*wz - uz*wy, ny = uz*wx - ux*wz, nz = ux*wy - uy*wx;
            atomicAdd(&pnn[3*i0+0], nx); atomicAdd(&pnn[3*i0+1], ny); atomicAdd(&pnn[3*i0+2], nz);
            atomicAdd(&pnn[3*i1+0], nx); atomicAdd(&pnn[3*i1+1], ny); atomicAdd(&pnn[3*i1+2], nz);
            atomicAdd(&pnn[3*i2+0], nx); atomicAdd(&pnn[3*i2+1], ny); atomicAdd(&pnn[3*i2+2], nz);
            atomicAdd(&nsum[3*i0+0], bx+cx); atomicAdd(&nsum[3*i0+1], by+cy); atomicAdd(&nsum[3*i0+2], bz+cz);
            atomicAdd(&nsum[3*i1+0], cx+ax); atomicAdd(&nsum[3*i1+1], cy+ay); atomicAdd(&nsum[3*i1+2], cz+az);
            atomicAdd(&nsum[3*i2+0], ax+bx); atomicAdd(&nsum[3*i2+1], ay+by); atomicAdd(&nsum[3*i2+2], az+bz);
            atomicAdd(&deg[i0], 2.0f); atomicAdd(&deg[i1], 2.0f); atomicAdd(&deg[i2], 2.0f);
        }
    }
}

__device__ __forceinline__ float wave_sum(float x) {
    #pragma unroll
    for (int o = 32; o > 0; o >>= 1) x += __shfl_down(x, o, 64);
    return x;
}

__device__ __forceinline__ unsigned long long u64min(unsigned long long a,
                                                     unsigned long long b) {
    return a < b ? a : b;
}

// Group-parallel NN: QL=16 lanes cooperate on one query. 27-neighborhood cells
// distributed across lanes; packed (d2bits<<32)|idx min-reduce == exact
// first-occurrence argmin. If the r=1 box bound fails (P~5e-6: no point within
// one cell width), exact brute-force fallback distributed over the group.
// Group-uniform branch -> intra-group shuffles safe.
__device__ __forceinline__ unsigned long long group_nn(int lane,
                                                       float px, float py, float pz,
                                                       const float4* __restrict__ S,
                                                       const unsigned* __restrict__ cstart,
                                                       const unsigned* __restrict__ cend,
                                                       int ntot) {
    int cx = cell_of(px), cy = cell_of(py), cz = cell_of(pz);
    unsigned long long best = 0xFFFFFFFFFFFFFFFFULL;
    #pragma unroll
    for (int k0 = 0; k0 < 2; ++k0) {
        int k = lane + k0 * QL;
        if (k < 27) {
            int dz = k / 9, dy = (k / 3) % 3, dx = k % 3;
            int z = cz + dz - 1, y = cy + dy - 1, x = cx + dx - 1;
            if (x >= 0 && x < GR && y >= 0 && y < GR && z >= 0 && z < GR) {
                int c = (z * GR + y) * GR + x;
                unsigned s0 = cstart[c], s1 = cend[c];
                for (unsigned t = s0; t < s1; ++t) {
                    float4 q = S[t];
                    float ddx = px - q.x, ddy = py - q.y, ddz = pz - q.z;
                    float d2 = fmaf(ddx, ddx, fmaf(ddy, ddy, ddz*ddz));
                    unsigned long long key =
                        ((unsigned long long)__float_as_uint(d2) << 32) |
                        (unsigned)__float_as_int(q.w);
                    best = u64min(best, key);
                }
            }
        }
    }
    #pragma unroll
    for (int m = 1; m < QL; m <<= 1)
        best = u64min(best, (unsigned long long)__shfl_xor((long long)best, m, 64));
    // lower bound on any point outside the scanned r=1 box (domain border -> inf)
    float blo = 1.0e30f;
    if (cx > 0)      blo = fminf(blo, px - (float)(cx - 1) * HCELL);
    if (cx < GR - 1) blo = fminf(blo, (float)(cx + 2) * HCELL - px);
    if (cy > 0)      blo = fminf(blo, py - (float)(cy - 1) * HCELL);
    if (cy < GR - 1) blo = fminf(blo, (float)(cy + 2) * HCELL - py);
    if (cz > 0)      blo = fminf(blo, pz - (float)(cz - 1) * HCELL);
    if (cz < GR - 1) blo = fminf(blo, (float)(cz + 2) * HCELL - pz);
    float bd2 = __uint_as_float((unsigned)(best >> 32));
    if (blo < 1.0e29f && bd2 > blo * blo) {
        for (int t = lane; t < ntot; t += QL) {
            float4 q = S[t];
            float ddx = px - q.x, ddy = py - q.y, ddz = pz - q.z;
            float d2 = fmaf(ddx, ddx, fmaf(ddy, ddy, ddz*ddz));
            unsigned long long key =
                ((unsigned long long)__float_as_uint(d2) << 32) |
                (unsigned)__float_as_int(q.w);
            best = u64min(best, key);
        }
        #pragma unroll
        for (int m = 1; m < QL; m <<= 1)
            best = u64min(best, (unsigned long long)__shfl_xor((long long)best, m, 64));
    }
    return best;
}

// Dispatch 3: group-parallel NN (16 lanes/query, sorted order) fused with all
// finalize terms; last block (atomic ticket) combines and writes d_out.
#define QPB (256 / QL)                       // 16 queries per block
#define PRED_QBLOCKS (NP / QPB)              // 512
#define GT_QBLOCKS (NG / QPB)                // 750
#define FIN_TOTAL (PRED_QBLOCKS + GT_QBLOCKS) // 1262
__global__ __launch_bounds__(256) void query_finalize_kernel(const float* __restrict__ relpos,
                                                             const int* __restrict__ label,
                                                             const float4* __restrict__ sortP,
                                                             const float4* __restrict__ sortG,
                                                             const unsigned* __restrict__ startP,
                                                             const unsigned* __restrict__ endP,
                                                             const unsigned* __restrict__ startG,
                                                             const unsigned* __restrict__ endG,
                                                             const float* __restrict__ pnn,
                                                             const float* __restrict__ gtn,
                                                             const float* __restrict__ nsum,
                                                             const float* __restrict__ deg,
                                                             float* __restrict__ scal,
                                                             unsigned* __restrict__ ticket,
                                                             float* __restrict__ out) {
    int lane = threadIdx.x & (QL - 1);
    int group = threadIdx.x >> 4;            // 0..15
    if (blockIdx.x < PRED_QBLOCKS) {
        int qid = blockIdx.x * QPB + group;  // < 8192 (exact)
        float4 P = sortP[qid];
        float px = P.x, py = P.y, pz = P.z;
        unsigned long long key = group_nn(lane, px, py, pz, sortG, startG, endG, NG);

        float r0 = 0.f, r1 = 0.f, r2 = 0.f, r3 = 0.f, r4 = 0.f, r5 = 0.f;
        if (lane == 0) {
            int v = __float_as_int(P.w);               // original pred index
            float dmin = __uint_as_float((unsigned)(key >> 32));
            int nearest = (int)(unsigned)(key & 0xffffffffu);

            // normal consistency (normalize both accumulators on the fly)
            float ax = pnn[3*v], ay = pnn[3*v+1], az = pnn[3*v+2];
            float an = fmaxf(sqrtf(ax*ax + ay*ay + az*az), EPSF);
            float gx = gtn[3*nearest], gy = gtn[3*nearest+1], gz = gtn[3*nearest+2];
            float gn = fmaxf(sqrtf(gx*gx + gy*gy + gz*gz), EPSF);
            float nx = ax/an - gx/gn, ny = ay/an - gy/gn, nz = az/an - gz/gn;
            float sse = nx*nx + ny*ny + nz*nz;

            // laplacian
            float d = fmaxf(deg[v], 1.0f);
            float lx = nsum[3*v]/d - px, ly = nsum[3*v+1]/d - py, lz = nsum[3*v+2]/d - pz;
            float lapn = sqrtf(lx*lx + ly*ly + lz*lz);

            // grid-sample target (nearest, align_corners=True, zeros padding)
            int ix = (int)rintf(px * 95.0f), iy = (int)rintf(py * 95.0f), iz = (int)rintf(pz * 95.0f);
            bool inb = (ix >= 0) & (ix < 96) & (iy >= 0) & (iy < 96) & (iz >= 0) & (iz < 96);
            int ixc = min(max(ix, 0), 95), iyc = min(max(iy, 0), 95), izc = min(max(iz, 0), 95);
            bool pos = inb && (label[(izc*96 + iyc)*96 + ixc] == 1);

            float p = fminf(fmaxf(relpos[v], EPSF), 1.0f - EPSF);
            float om = 1.0f - p;
            float pcnt = 0.0f, sx = 0.0f, sy = 0.0f;
            if (pos) { pcnt = 1.0f; sx = om*om*logf(p); }
            else     { sy = p*p*logf(om); }

            r0 = dmin; r1 = sse; r2 = lapn; r3 = pcnt; r4 = sx; r5 = sy;
        }
        r0 = wave_sum(r0); r1 = wave_sum(r1); r2 = wave_sum(r2);
        r3 = wave_sum(r3); r4 = wave_sum(r4); r5 = wave_sum(r5);
        if ((threadIdx.x & 63) == 0) {
            atomicAdd(&scal[0], r0);
            atomicAdd(&scal[5], r1);
            atomicAdd(&scal[6], r2);
            atomicAdd(&scal[2], r3);
            atomicAdd(&scal[3], r4);
            atomicAdd(&scal[4], r5);
        }
    } else {
        int qid = (blockIdx.x - PRED_QBLOCKS) * QPB + group;  // < 12000 (exact)
        float4 Q = sortG[qid];
        unsigned long long key = group_nn(lane, Q.x, Q.y, Q.z, sortP, startP, endP, NP);
        float val = (lane == 0) ? __uint_as_float((unsigned)(key >> 32)) : 0.0f;
        float r = wave_sum(val);
        if ((threadIdx.x & 63) == 0) atomicAdd(&scal[1], r);
    }

    // last-block combine (device-scope atomics; fence orders our adds before ticket)
    __threadfence();
    __shared__ int is_last;
    if (threadIdx.x == 0) {
        unsigned t = atomicAdd(ticket, 1u);
        is_last = (t == FIN_TOTAL - 1) ? 1 : 0;
    }
    __syncthreads();
    if (is_last && threadIdx.x == 0) {
        float sum_row = atomicAdd(&scal[0], 0.0f);
        float sum_col = atomicAdd(&scal[1], 0.0f);
        float pc      = atomicAdd(&scal[2], 0.0f);
        float SX      = atomicAdd(&scal[3], 0.0f);
        float SY      = atomicAdd(&scal[4], 0.0f);
        float sse     = atomicAdd(&scal[5], 0.0f);
        float lap     = atomicAdd(&scal[6], 0.0f);
        float tot = (float)NP;
        float alpha = (tot - pc) / (tot + EPSF);
        float spatial = (-alpha * SX - (1.0f - alpha) * SY) / (tot + EPSF);
        float distance = sum_row / (float)NP + sum_col / (float)NG;
        float normal = sse / (float)(NP * 3);
        float lapm = lap / (float)NP;
        out[0] = spatial + 1.0f * distance + 0.01f * normal + 0.1f * lapm;
    }
}

extern "C" void kernel_launch(void* const* d_in, const int* in_sizes, int n_in,
                              void* d_out, int out_size, void* d_ws, size_t ws_size,
                              hipStream_t stream) {
    const float* pred   = (const float*)d_in[0];   // [8192,3]
    const float* relpos = (const float*)d_in[1];   // [8192]
    const float* gt     = (const float*)d_in[2];   // [12000,3]
    const int*   pfaces = (const int*)d_in[3];     // [16384,3]
    const int*   gfaces = (const int*)d_in[4];     // [24000,3]
    const int*   label  = (const int*)d_in[5];     // [1,1,96,96,96]
    float* out = (float*)d_out;

    char* ws = (char*)d_ws;
    unsigned* startP = (unsigned*)(ws + OFF_STARTP);
    unsigned* curP   = (unsigned*)(ws + OFF_CURP);
    unsigned* startG = (unsigned*)(ws + OFF_STARTG);
    unsigned* curG   = (unsigned*)(ws + OFF_CURG);
    float4*   sortP  = (float4*)(ws + OFF_SORTP);
    float4*   sortG  = (float4*)(ws + OFF_SORTG);
    float*    gtn    = (float*)(ws + OFF_GTN);
    float*    pnn    = (float*)(ws + OFF_PNN);
    float*    nsum   = (float*)(ws + OFF_NSUM);
    float*    deg    = (float*)(ws + OFF_DEG);
    float*    scal   = (float*)(ws + OFF_SCAL);
    unsigned* ticket = (unsigned*)(ws + OFF_TICKET);

    // d1: build histograms+scans (blocks 0,1) || zero accumulators (blocks 2..)
    int zero_blocks = (N_ZERO + 1023) / 1024;      // 92
    hipLaunchKernelGGL(build_kernel, dim3(2 + zero_blocks), dim3(1024), 0, stream,
                       pred, gt, startP, curP, startG, curG, gtn);
    // d2: scatter into cell order + face/laplacian scatter
    hipLaunchKernelGGL(scatter_faces_kernel, dim3(SCAT_BLOCKS + FACE_BLOCKS), dim3(256), 0, stream,
                       pred, pfaces, gt, gfaces, curP, curG, sortP, sortG,
                       gtn, pnn, nsum, deg);
    // d3: group-parallel grid-NN + all loss terms + combine
    hipLaunchKernelGGL(query_finalize_kernel, dim3(FIN_TOTAL), dim3(256), 0, stream,
                       relpos, label, sortP, sortG, startP, curP, startG, curG,
                       pnn, gtn, nsum, deg, scal, ticket, out);
}

// Round 7
// 180.756 us; speedup vs baseline: 1.8827x; 1.8827x over previous
//
#include <hip/hip_runtime.h>
#include <math.h>

// Problem constants (fixed by setup_inputs)
#define NP 8192      // pred vertices
#define NG 12000     // gt vertices
#define NFP 16384    // pred faces
#define NFG 24000    // gt faces
#define EPSF 1e-6f

// uniform grid for NN: 16^3 cells over [0,1]^3, ~3 gt / ~2 pred per cell
#define GR 16
#define NC (GR*GR*GR)        // 4096
#define HCELL 0.0625f        // 1/16, exact power of two
#define QL 16                // lanes cooperating per NN query
#define QPB (256 / QL)       // 16 queries per block
#define PRED_QBLOCKS (NP / QPB)               // 512
#define GT_QBLOCKS (NG / QPB)                 // 750
#define FIN_TOTAL (PRED_QBLOCKS + GT_QBLOCKS) // 1262

// ---- workspace layout (bytes) ----
static constexpr size_t OFF_STARTP = 0;        // (NC+1) u32 cell start (pred), [NC]=NP
static constexpr size_t OFF_CURP   = 16640;    // NC u32 scatter cursor
static constexpr size_t OFF_STARTG = 33024;    // (NC+1) u32 cell start (gt), [NC]=NG
static constexpr size_t OFF_CURG   = 49664;    // NC u32 scatter cursor
static constexpr size_t OFF_SORTP  = 66048;    // 8192  float4 (x,y,z,idx-as-float-bits)
static constexpr size_t OFF_SORTG  = 197120;   // 12000 float4
static constexpr size_t OFF_GTN    = 389120;   // NG*3 f32 gt normal accum (raw)
static constexpr size_t OFF_PNN    = 533120;   // NP*3 f32 pred normal accum
static constexpr size_t OFF_NSUM   = 631424;   // NP*3 f32 laplacian neighbor sum
static constexpr size_t OFF_DEG    = 729728;   // NP   f32 laplacian degree
static constexpr size_t OFF_PART   = 762496;   // FIN_TOTAL x 8 f32 per-block partials
#define N_ZERO 93344   // floats gtn..deg (contiguous); partials need no zeroing

__device__ __forceinline__ int cell_of(float x) {
    int c = (int)(x * (float)GR);
    return min(max(c, 0), GR - 1);
}

// histogram + exclusive scan of one point set into start/cur (1024-thread block)
__device__ __forceinline__ void hist_scan(const float* __restrict__ pts, int n,
                                          unsigned* __restrict__ start,
                                          unsigned* __restrict__ cur,
                                          unsigned* h, unsigned* ps) {
    int t = threadIdx.x;
    for (int i = t; i < NC; i += 1024) h[i] = 0u;
    __syncthreads();
    for (int i = t; i < n; i += 1024) {
        int c = (cell_of(pts[3*i+2]) * GR + cell_of(pts[3*i+1])) * GR + cell_of(pts[3*i]);
        atomicAdd(&h[c], 1u);
    }
    __syncthreads();
    unsigned a0 = h[4*t], a1 = h[4*t+1], a2 = h[4*t+2], a3 = h[4*t+3];
    unsigned tsum = a0 + a1 + a2 + a3;
    ps[t] = tsum; __syncthreads();
    for (int off = 1; off < 1024; off <<= 1) {
        unsigned v = (t >= off) ? ps[t - off] : 0u;
        __syncthreads();
        ps[t] += v;
        __syncthreads();
    }
    unsigned ex = ps[t] - tsum;
    h[4*t] = ex; h[4*t+1] = ex + a0; h[4*t+2] = ex + a0 + a1; h[4*t+3] = ex + a0 + a1 + a2;
    __syncthreads();
    for (int i = t; i < NC; i += 1024) { start[i] = h[i]; cur[i] = h[i]; }
    if (t == 0) start[NC] = (unsigned)n;   // end sentinel: end[c] == start[c+1]
}

// Dispatch 1: block 0 = pred histogram+scan, block 1 = gt histogram+scan,
//             blocks >=2 = zero the accumulator region.
__global__ __launch_bounds__(1024) void build_kernel(const float* __restrict__ pred,
                                                     const float* __restrict__ gt,
                                                     unsigned* __restrict__ startP,
                                                     unsigned* __restrict__ curP,
                                                     unsigned* __restrict__ startG,
                                                     unsigned* __restrict__ curG,
                                                     float* __restrict__ zero) {
    __shared__ unsigned h[NC];
    __shared__ unsigned ps[1024];
    if (blockIdx.x == 0) {
        hist_scan(pred, NP, startP, curP, h, ps);
    } else if (blockIdx.x == 1) {
        hist_scan(gt, NG, startG, curG, h, ps);
    } else {
        int i = (blockIdx.x - 2) * 1024 + threadIdx.x;
        if (i < N_ZERO) zero[i] = 0.0f;
    }
}

// Dispatch 2: scatter points into cell-sorted arrays + face-normal/laplacian scatter.
#define SCAT_P_BLOCKS 32                        // 8192/256
#define SCAT_G_BLOCKS 47                        // ceil(12000/256)
#define SCAT_BLOCKS (SCAT_P_BLOCKS + SCAT_G_BLOCKS)
#define FACE_BLOCKS ((NFG + NFP + 255) / 256)   // 158
__global__ __launch_bounds__(256) void scatter_faces_kernel(const float* __restrict__ pred,
                                                            const int* __restrict__ pf,
                                                            const float* __restrict__ gt,
                                                            const int* __restrict__ gf,
                                                            unsigned* __restrict__ curP,
                                                            unsigned* __restrict__ curG,
                                                            float4* __restrict__ sortP,
                                                            float4* __restrict__ sortG,
                                                            float* __restrict__ gtn,
                                                            float* __restrict__ pnn,
                                                            float* __restrict__ nsum,
                                                            float* __restrict__ deg) {
    int b = blockIdx.x;
    if (b < SCAT_P_BLOCKS) {
        int i = b * 256 + threadIdx.x;            // < 8192 always
        float x = pred[3*i], y = pred[3*i+1], z = pred[3*i+2];
        int c = (cell_of(z) * GR + cell_of(y)) * GR + cell_of(x);
        unsigned pos = atomicAdd(&curP[c], 1u);
        sortP[pos] = make_float4(x, y, z, __int_as_float(i));
    } else if (b < SCAT_BLOCKS) {
        int i = (b - SCAT_P_BLOCKS) * 256 + threadIdx.x;
        if (i < NG) {
            float x = gt[3*i], y = gt[3*i+1], z = gt[3*i+2];
            int c = (cell_of(z) * GR + cell_of(y)) * GR + cell_of(x);
            unsigned pos = atomicAdd(&curG[c], 1u);
            sortG[pos] = make_float4(x, y, z, __int_as_float(i));
        }
    } else {
        int t = (b - SCAT_BLOCKS) * 256 + threadIdx.x;
        if (t < NFG) {
            int i0 = gf[3*t], i1 = gf[3*t+1], i2 = gf[3*t+2];
            float ax = gt[3*i0], ay = gt[3*i0+1], az = gt[3*i0+2];
            float bx = gt[3*i1], by = gt[3*i1+1], bz = gt[3*i1+2];
            float cx = gt[3*i2], cy = gt[3*i2+1], cz = gt[3*i2+2];
            float ux = bx-ax, uy = by-ay, uz = bz-az;
            float wx = cx-ax, wy = cy-ay, wz = cz-az;
            float nx = uy*wz - uz*wy, ny = uz*wx - ux*wz, nz = ux*wy - uy*wx;
            atomicAdd(&gtn[3*i0+0], nx); atomicAdd(&gtn[3*i0+1], ny); atomicAdd(&gtn[3*i0+2], nz);
            atomicAdd(&gtn[3*i1+0], nx); atomicAdd(&gtn[3*i1+1], ny); atomicAdd(&gtn[3*i1+2], nz);
            atomicAdd(&gtn[3*i2+0], nx); atomicAdd(&gtn[3*i2+1], ny); atomicAdd(&gtn[3*i2+2], nz);
        } else if (t < NFG + NFP) {
            int u = t - NFG;
            int i0 = pf[3*u], i1 = pf[3*u+1], i2 = pf[3*u+2];
            float ax = pred[3*i0], ay = pred[3*i0+1], az = pred[3*i0+2];
            float bx = pred[3*i1], by = pred[3*i1+1], bz = pred[3*i1+2];
            float cx = pred[3*i2], cy = pred[3*i2+1], cz = pred[3*i2+2];
            float ux = bx-ax, uy = by-ay, uz = bz-az;
            float wx = cx-ax, wy = cy-ay, wz = cz-az;
            float nx = uy*wz - uz*wy, ny = uz*wx - ux*wz, nz = ux*wy - uy*wx;
            atomicAdd(&pnn[3*i0+0], nx); atomicAdd(&pnn[3*i0+1], ny); atomicAdd(&pnn[3*i0+2], nz);
            atomicAdd(&pnn[3*i1+0], nx); atomicAdd(&pnn[3*i1+1], ny); atomicAdd(&pnn[3*i1+2], nz);
            atomicAdd(&pnn[3*i2+0], nx); atomicAdd(&pnn[3*i2+1], ny); atomicAdd(&pnn[3*i2+2], nz);
            atomicAdd(&nsum[3*i0+0], bx+cx); atomicAdd(&nsum[3*i0+1], by+cy); atomicAdd(&nsum[3*i0+2], bz+cz);
            atomicAdd(&nsum[3*i1+0], cx+ax); atomicAdd(&nsum[3*i1+1], cy+ay); atomicAdd(&nsum[3*i1+2], cz+az);
            atomicAdd(&nsum[3*i2+0], ax+bx); atomicAdd(&nsum[3*i2+1], ay+by); atomicAdd(&nsum[3*i2+2], az+bz);
            atomicAdd(&deg[i0], 2.0f); atomicAdd(&deg[i1], 2.0f); atomicAdd(&deg[i2], 2.0f);
        }
    }
}

__device__ __forceinline__ float wave_sum(float x) {
    #pragma unroll
    for (int o = 32; o > 0; o >>= 1) x += __shfl_down(x, o, 64);
    return x;
}

__device__ __forceinline__ unsigned long long u64min(unsigned long long a,
                                                     unsigned long long b) {
    return a < b ? a : b;
}

// Group-parallel NN, span form: cells are scan-ordered, so the 3 x-adjacent
// cells of each (z,y) row are one CONTIGUOUS point range [start[c0], start[c1+1]).
// Lanes 0..8 each walk one (z,y) span; packed (d2bits<<32)|idx min-reduce over
// the 16-lane group == exact first-occurrence argmin. If the r=1 box bound
// fails (P~1e-4: no point within one cell width), exact brute-force fallback
// (group-uniform branch: px,py,pz and reduced best are identical group-wide).
__device__ __forceinline__ unsigned long long group_nn(int lane,
                                                       float px, float py, float pz,
                                                       const float4* __restrict__ S,
                                                       const unsigned* __restrict__ cstart,
                                                       int ntot) {
    int cx = cell_of(px), cy = cell_of(py), cz = cell_of(pz);
    unsigned long long best = 0xFFFFFFFFFFFFFFFFULL;
    if (lane < 9) {
        int dz = lane / 3 - 1, dy = lane % 3 - 1;
        int z = cz + dz, y = cy + dy;
        if (z >= 0 && z < GR && y >= 0 && y < GR) {
            int rowbase = (z * GR + y) * GR;
            int x0 = max(cx - 1, 0), x1 = min(cx + 1, GR - 1);
            unsigned s0 = cstart[rowbase + x0];
            unsigned s1 = cstart[rowbase + x1 + 1];
            for (unsigned t = s0; t < s1; ++t) {
                float4 q = S[t];
                float ddx = px - q.x, ddy = py - q.y, ddz = pz - q.z;
                float d2 = fmaf(ddx, ddx, fmaf(ddy, ddy, ddz*ddz));
                unsigned long long key =
                    ((unsigned long long)__float_as_uint(d2) << 32) |
                    (unsigned)__float_as_int(q.w);
                best = u64min(best, key);
            }
        }
    }
    #pragma unroll
    for (int m = 1; m < QL; m <<= 1)
        best = u64min(best, (unsigned long long)__shfl_xor((long long)best, m, 64));
    // lower bound on any point outside the scanned r=1 box (domain border -> inf)
    float blo = 1.0e30f;
    if (cx > 0)      blo = fminf(blo, px - (float)(cx - 1) * HCELL);
    if (cx < GR - 1) blo = fminf(blo, (float)(cx + 2) * HCELL - px);
    if (cy > 0)      blo = fminf(blo, py - (float)(cy - 1) * HCELL);
    if (cy < GR - 1) blo = fminf(blo, (float)(cy + 2) * HCELL - py);
    if (cz > 0)      blo = fminf(blo, pz - (float)(cz - 1) * HCELL);
    if (cz < GR - 1) blo = fminf(blo, (float)(cz + 2) * HCELL - pz);
    float bd2 = __uint_as_float((unsigned)(best >> 32));
    if (blo < 1.0e29f && bd2 > blo * blo) {
        for (int t = lane; t < ntot; t += QL) {
            float4 q = S[t];
            float ddx = px - q.x, ddy = py - q.y, ddz = pz - q.z;
            float d2 = fmaf(ddx, ddx, fmaf(ddy, ddy, ddz*ddz));
            unsigned long long key =
                ((unsigned long long)__float_as_uint(d2) << 32) |
                (unsigned)__float_as_int(q.w);
            best = u64min(best, key);
        }
        #pragma unroll
        for (int m = 1; m < QL; m <<= 1)
            best = u64min(best, (unsigned long long)__shfl_xor((long long)best, m, 64));
    }
    return best;
}

// Dispatch 3: group-parallel NN + per-query terms. NO global atomics/fences:
// block partials go wave->LDS->one plain store to partial[blockIdx].
__global__ __launch_bounds__(256) void query_kernel(const float* __restrict__ relpos,
                                                    const int* __restrict__ label,
                                                    const float4* __restrict__ sortP,
                                                    const float4* __restrict__ sortG,
                                                    const unsigned* __restrict__ startP,
                                                    const unsigned* __restrict__ startG,
                                                    const float* __restrict__ pnn,
                                                    const float* __restrict__ gtn,
                                                    const float* __restrict__ nsum,
                                                    const float* __restrict__ deg,
                                                    float* __restrict__ partial) {
    __shared__ float bsum[6];
    if (threadIdx.x < 6) bsum[threadIdx.x] = 0.0f;
    __syncthreads();
    int lane = threadIdx.x & (QL - 1);
    int group = threadIdx.x >> 4;            // 0..15
    if (blockIdx.x < PRED_QBLOCKS) {
        int qid = blockIdx.x * QPB + group;  // < 8192 (exact)
        float4 P = sortP[qid];
        float px = P.x, py = P.y, pz = P.z;
        unsigned long long key = group_nn(lane, px, py, pz, sortG, startG, NG);

        float r0 = 0.f, r1 = 0.f, r2 = 0.f, r3 = 0.f, r4 = 0.f, r5 = 0.f;
        if (lane == 0) {
            int v = __float_as_int(P.w);               // original pred index
            float dmin = __uint_as_float((unsigned)(key >> 32));
            int nearest = (int)(unsigned)(key & 0xffffffffu);

            // normal consistency (normalize both accumulators on the fly)
            float ax = pnn[3*v], ay = pnn[3*v+1], az = pnn[3*v+2];
            float an = fmaxf(sqrtf(ax*ax + ay*ay + az*az), EPSF);
            float gx = gtn[3*nearest], gy = gtn[3*nearest+1], gz = gtn[3*nearest+2];
            float gn = fmaxf(sqrtf(gx*gx + gy*gy + gz*gz), EPSF);
            float nx = ax/an - gx/gn, ny = ay/an - gy/gn, nz = az/an - gz/gn;
            float sse = nx*nx + ny*ny + nz*nz;

            // laplacian
            float d = fmaxf(deg[v], 1.0f);
            float lx = nsum[3*v]/d - px, ly = nsum[3*v+1]/d - py, lz = nsum[3*v+2]/d - pz;
            float lapn = sqrtf(lx*lx + ly*ly + lz*lz);

            // grid-sample target (nearest, align_corners=True, zeros padding)
            int ix = (int)rintf(px * 95.0f), iy = (int)rintf(py * 95.0f), iz = (int)rintf(pz * 95.0f);
            bool inb = (ix >= 0) & (ix < 96) & (iy >= 0) & (iy < 96) & (iz >= 0) & (iz < 96);
            int ixc = min(max(ix, 0), 95), iyc = min(max(iy, 0), 95), izc = min(max(iz, 0), 95);
            bool pos = inb && (label[(izc*96 + iyc)*96 + ixc] == 1);

            float p = fminf(fmaxf(relpos[v], EPSF), 1.0f - EPSF);
            float om = 1.0f - p;
            float pcnt = 0.0f, sx = 0.0f, sy = 0.0f;
            if (pos) { pcnt = 1.0f; sx = om*om*logf(p); }
            else     { sy = p*p*logf(om); }

            r0 = dmin; r1 = sse; r2 = lapn; r3 = pcnt; r4 = sx; r5 = sy;
        }
        r0 = wave_sum(r0); r1 = wave_sum(r1); r2 = wave_sum(r2);
        r3 = wave_sum(r3); r4 = wave_sum(r4); r5 = wave_sum(r5);
        if ((threadIdx.x & 63) == 0) {       // 4 wave leaders -> LDS atomics (cheap)
            atomicAdd(&bsum[0], r0); atomicAdd(&bsum[1], r1);
            atomicAdd(&bsum[2], r2); atomicAdd(&bsum[3], r3);
            atomicAdd(&bsum[4], r4); atomicAdd(&bsum[5], r5);
        }
        __syncthreads();
        if (threadIdx.x < 6)
            partial[(size_t)blockIdx.x * 8 + threadIdx.x] = bsum[threadIdx.x];
    } else {
        int qid = (blockIdx.x - PRED_QBLOCKS) * QPB + group;  // < 12000 (exact)
        float4 Q = sortG[qid];
        unsigned long long key = group_nn(lane, Q.x, Q.y, Q.z, sortP, startP, NP);
        float val = (lane == 0) ? __uint_as_float((unsigned)(key >> 32)) : 0.0f;
        float r = wave_sum(val);
        if ((threadIdx.x & 63) == 0) atomicAdd(&bsum[0], r);
        __syncthreads();
        if (threadIdx.x == 0)
            partial[(size_t)blockIdx.x * 8] = bsum[0];
    }
}

// Dispatch 4: one block reduces the partial table and writes the final scalar.
__global__ __launch_bounds__(256) void combine_kernel(const float* __restrict__ partial,
                                                      float* __restrict__ out) {
    float s0=0.f, s1=0.f, s2=0.f, s3=0.f, s4=0.f, s5=0.f, s6=0.f;
    for (int r = threadIdx.x; r < FIN_TOTAL; r += 256) {
        const float* p = partial + (size_t)r * 8;
        if (r < PRED_QBLOCKS) {
            s0 += p[0]; s1 += p[1]; s2 += p[2];
            s3 += p[3]; s4 += p[4]; s5 += p[5];
        } else {
            s6 += p[0];
        }
    }
    s0 = wave_sum(s0); s1 = wave_sum(s1); s2 = wave_sum(s2); s3 = wave_sum(s3);
    s4 = wave_sum(s4); s5 = wave_sum(s5); s6 = wave_sum(s6);
    __shared__ float acc[7];
    if (threadIdx.x < 7) acc[threadIdx.x] = 0.0f;
    __syncthreads();
    if ((threadIdx.x & 63) == 0) {
        atomicAdd(&acc[0], s0); atomicAdd(&acc[1], s1); atomicAdd(&acc[2], s2);
        atomicAdd(&acc[3], s3); atomicAdd(&acc[4], s4); atomicAdd(&acc[5], s5);
        atomicAdd(&acc[6], s6);
    }
    __syncthreads();
    if (threadIdx.x == 0) {
        float sum_row = acc[0], sse = acc[1], lap = acc[2];
        float pc = acc[3], SX = acc[4], SY = acc[5], sum_col = acc[6];
        float tot = (float)NP;
        float alpha = (tot - pc) / (tot + EPSF);
        float spatial = (-alpha * SX - (1.0f - alpha) * SY) / (tot + EPSF);
        float distance = sum_row / (float)NP + sum_col / (float)NG;
        float normal = sse / (float)(NP * 3);
        float lapm = lap / (float)NP;
        out[0] = spatial + 1.0f * distance + 0.01f * normal + 0.1f * lapm;
    }
}

extern "C" void kernel_launch(void* const* d_in, const int* in_sizes, int n_in,
                              void* d_out, int out_size, void* d_ws, size_t ws_size,
                              hipStream_t stream) {
    const float* pred   = (const float*)d_in[0];   // [8192,3]
    const float* relpos = (const float*)d_in[1];   // [8192]
    const float* gt     = (const float*)d_in[2];   // [12000,3]
    const int*   pfaces = (const int*)d_in[3];     // [16384,3]
    const int*   gfaces = (const int*)d_in[4];     // [24000,3]
    const int*   label  = (const int*)d_in[5];     // [1,1,96,96,96]
    float* out = (float*)d_out;

    char* ws = (char*)d_ws;
    unsigned* startP  = (unsigned*)(ws + OFF_STARTP);
    unsigned* curP    = (unsigned*)(ws + OFF_CURP);
    unsigned* startG  = (unsigned*)(ws + OFF_STARTG);
    unsigned* curG    = (unsigned*)(ws + OFF_CURG);
    float4*   sortP   = (float4*)(ws + OFF_SORTP);
    float4*   sortG   = (float4*)(ws + OFF_SORTG);
    float*    gtn     = (float*)(ws + OFF_GTN);
    float*    pnn     = (float*)(ws + OFF_PNN);
    float*    nsum    = (float*)(ws + OFF_NSUM);
    float*    deg     = (float*)(ws + OFF_DEG);
    float*    partial = (float*)(ws + OFF_PART);

    // d1: build histograms+scans (blocks 0,1) || zero accumulators (blocks 2..)
    int zero_blocks = (N_ZERO + 1023) / 1024;      // 92
    hipLaunchKernelGGL(build_kernel, dim3(2 + zero_blocks), dim3(1024), 0, stream,
                       pred, gt, startP, curP, startG, curG, gtn);
    // d2: scatter into cell order + face/laplacian scatter
    hipLaunchKernelGGL(scatter_faces_kernel, dim3(SCAT_BLOCKS + FACE_BLOCKS), dim3(256), 0, stream,
                       pred, pfaces, gt, gfaces, curP, curG, sortP, sortG,
                       gtn, pnn, nsum, deg);
    // d3: group-parallel grid-NN + per-query terms -> per-block partials
    hipLaunchKernelGGL(query_kernel, dim3(FIN_TOTAL), dim3(256), 0, stream,
                       relpos, label, sortP, sortG, startP, startG,
                       pnn, gtn, nsum, deg, partial);
    // d4: reduce partials + final combine
    hipLaunchKernelGGL(combine_kernel, dim3(1), dim3(256), 0, stream, partial, out);
}

// Round 8
// 116.333 us; speedup vs baseline: 2.9253x; 1.5538x over previous
//
#include <hip/hip_runtime.h>
#include <math.h>

// Problem constants (fixed by setup_inputs)
#define NP 8192      // pred vertices
#define NG 12000     // gt vertices
#define NFP 16384    // pred faces
#define NFG 24000    // gt faces
#define EPSF 1e-6f

// uniform grid for NN: 16^3 cells over [0,1]^3, ~3 gt / ~2 pred per cell
#define GR 16
#define NC (GR*GR*GR)        // 4096
#define HCELL 0.0625f        // 1/16, exact power of two
#define QL 16                // lanes cooperating per NN query
#define QPB (256 / QL)       // 16 queries per block
#define PRED_QBLOCKS (NP / QPB)               // 512
#define GT_QBLOCKS (NG / QPB)                 // 750
#define FIN_TOTAL (PRED_QBLOCKS + GT_QBLOCKS) // 1262

// ---- workspace layout (bytes) ----
static constexpr size_t OFF_STARTP = 0;        // (NC+1) u32 cell start (pred), [NC]=NP
static constexpr size_t OFF_CURP   = 16640;    // NC u32 scatter cursor
static constexpr size_t OFF_STARTG = 33024;    // (NC+1) u32 cell start (gt), [NC]=NG
static constexpr size_t OFF_CURG   = 49664;    // NC u32 scatter cursor
static constexpr size_t OFF_SORTP  = 66048;    // 8192  float4 (x,y,z,idx-as-float-bits)
static constexpr size_t OFF_SORTG  = 197120;   // 12000 float4
static constexpr size_t OFF_GTN    = 389120;   // NG*3 f32 gt normal accum (raw)
static constexpr size_t OFF_PNN    = 533120;   // NP*3 f32 pred normal accum
static constexpr size_t OFF_NSUM   = 631424;   // NP*3 f32 laplacian neighbor sum
static constexpr size_t OFF_DEG    = 729728;   // NP   f32 laplacian degree
static constexpr size_t OFF_PART   = 762496;   // FIN_TOTAL x 8 f32 per-block partials
#define N_ZERO 93344   // floats gtn..deg (contiguous); partials need no zeroing

__device__ __forceinline__ int cell_of(float x) {
    int c = (int)(x * (float)GR);
    return min(max(c, 0), GR - 1);
}

// histogram + exclusive scan of one point set into start/cur (1024-thread block)
__device__ __forceinline__ void hist_scan(const float* __restrict__ pts, int n,
                                          unsigned* __restrict__ start,
                                          unsigned* __restrict__ cur,
                                          unsigned* h, unsigned* ps) {
    int t = threadIdx.x;
    for (int i = t; i < NC; i += 1024) h[i] = 0u;
    __syncthreads();
    for (int i = t; i < n; i += 1024) {
        int c = (cell_of(pts[3*i+2]) * GR + cell_of(pts[3*i+1])) * GR + cell_of(pts[3*i]);
        atomicAdd(&h[c], 1u);
    }
    __syncthreads();
    unsigned a0 = h[4*t], a1 = h[4*t+1], a2 = h[4*t+2], a3 = h[4*t+3];
    unsigned tsum = a0 + a1 + a2 + a3;
    ps[t] = tsum; __syncthreads();
    for (int off = 1; off < 1024; off <<= 1) {
        unsigned v = (t >= off) ? ps[t - off] : 0u;
        __syncthreads();
        ps[t] += v;
        __syncthreads();
    }
    unsigned ex = ps[t] - tsum;
    h[4*t] = ex; h[4*t+1] = ex + a0; h[4*t+2] = ex + a0 + a1; h[4*t+3] = ex + a0 + a1 + a2;
    __syncthreads();
    for (int i = t; i < NC; i += 1024) { start[i] = h[i]; cur[i] = h[i]; }
    if (t == 0) start[NC] = (unsigned)n;   // end sentinel: end[c] == start[c+1]
}

// Dispatch 1: block 0 = pred histogram+scan, block 1 = gt histogram+scan,
//             blocks >=2 = zero the accumulator region.
__global__ __launch_bounds__(1024) void build_kernel(const float* __restrict__ pred,
                                                     const float* __restrict__ gt,
                                                     unsigned* __restrict__ startP,
                                                     unsigned* __restrict__ curP,
                                                     unsigned* __restrict__ startG,
                                                     unsigned* __restrict__ curG,
                                                     float* __restrict__ zero) {
    __shared__ unsigned h[NC];
    __shared__ unsigned ps[1024];
    if (blockIdx.x == 0) {
        hist_scan(pred, NP, startP, curP, h, ps);
    } else if (blockIdx.x == 1) {
        hist_scan(gt, NG, startG, curG, h, ps);
    } else {
        int i = (blockIdx.x - 2) * 1024 + threadIdx.x;
        if (i < N_ZERO) zero[i] = 0.0f;
    }
}

// Dispatch 2: scatter points into cell-sorted arrays + face-normal/laplacian scatter.
#define SCAT_P_BLOCKS 32                        // 8192/256
#define SCAT_G_BLOCKS 47                        // ceil(12000/256)
#define SCAT_BLOCKS (SCAT_P_BLOCKS + SCAT_G_BLOCKS)
#define FACE_BLOCKS ((NFG + NFP + 255) / 256)   // 158
__global__ __launch_bounds__(256) void scatter_faces_kernel(const float* __restrict__ pred,
                                                            const int* __restrict__ pf,
                                                            const float* __restrict__ gt,
                                                            const int* __restrict__ gf,
                                                            unsigned* __restrict__ curP,
                                                            unsigned* __restrict__ curG,
                                                            float4* __restrict__ sortP,
                                                            float4* __restrict__ sortG,
                                                            float* __restrict__ gtn,
                                                            float* __restrict__ pnn,
                                                            float* __restrict__ nsum,
                                                            float* __restrict__ deg) {
    int b = blockIdx.x;
    if (b < SCAT_P_BLOCKS) {
        int i = b * 256 + threadIdx.x;            // < 8192 always
        float x = pred[3*i], y = pred[3*i+1], z = pred[3*i+2];
        int c = (cell_of(z) * GR + cell_of(y)) * GR + cell_of(x);
        unsigned pos = atomicAdd(&curP[c], 1u);
        sortP[pos] = make_float4(x, y, z, __int_as_float(i));
    } else if (b < SCAT_BLOCKS) {
        int i = (b - SCAT_P_BLOCKS) * 256 + threadIdx.x;
        if (i < NG) {
            float x = gt[3*i], y = gt[3*i+1], z = gt[3*i+2];
            int c = (cell_of(z) * GR + cell_of(y)) * GR + cell_of(x);
            unsigned pos = atomicAdd(&curG[c], 1u);
            sortG[pos] = make_float4(x, y, z, __int_as_float(i));
        }
    } else {
        int t = (b - SCAT_BLOCKS) * 256 + threadIdx.x;
        if (t < NFG) {
            int i0 = gf[3*t], i1 = gf[3*t+1], i2 = gf[3*t+2];
            float ax = gt[3*i0], ay = gt[3*i0+1], az = gt[3*i0+2];
            float bx = gt[3*i1], by = gt[3*i1+1], bz = gt[3*i1+2];
            float cx = gt[3*i2], cy = gt[3*i2+1], cz = gt[3*i2+2];
            float ux = bx-ax, uy = by-ay, uz = bz-az;
            float wx = cx-ax, wy = cy-ay, wz = cz-az;
            float nx = uy*wz - uz*wy, ny = uz*wx - ux*wz, nz = ux*wy - uy*wx;
            atomicAdd(&gtn[3*i0+0], nx); atomicAdd(&gtn[3*i0+1], ny); atomicAdd(&gtn[3*i0+2], nz);
            atomicAdd(&gtn[3*i1+0], nx); atomicAdd(&gtn[3*i1+1], ny); atomicAdd(&gtn[3*i1+2], nz);
            atomicAdd(&gtn[3*i2+0], nx); atomicAdd(&gtn[3*i2+1], ny); atomicAdd(&gtn[3*i2+2], nz);
        } else if (t < NFG + NFP) {
            int u = t - NFG;
            int i0 = pf[3*u], i1 = pf[3*u+1], i2 = pf[3*u+2];
            float ax = pred[3*i0], ay = pred[3*i0+1], az = pred[3*i0+2];
            float bx = pred[3*i1], by = pred[3*i1+1], bz = pred[3*i1+2];
            float cx = pred[3*i2], cy = pred[3*i2+1], cz = pred[3*i2+2];
            float ux = bx-ax, uy = by-ay, uz = bz-az;
            float wx = cx-ax, wy = cy-ay, wz = cz-az;
            float nx = uy*wz - uz*wy, ny = uz*wx - ux*wz, nz = ux*wy - uy*wx;
            atomicAdd(&pnn[3*i0+0], nx); atomicAdd(&pnn[3*i0+1], ny); atomicAdd(&pnn[3*i0+2], nz);
            atomicAdd(&pnn[3*i1+0], nx); atomicAdd(&pnn[3*i1+1], ny); atomicAdd(&pnn[3*i1+2], nz);
            atomicAdd(&pnn[3*i2+0], nx); atomicAdd(&pnn[3*i2+1], ny); atomicAdd(&pnn[3*i2+2], nz);
            atomicAdd(&nsum[3*i0+0], bx+cx); atomicAdd(&nsum[3*i0+1], by+cy); atomicAdd(&nsum[3*i0+2], bz+cz);
            atomicAdd(&nsum[3*i1+0], cx+ax); atomicAdd(&nsum[3*i1+1], cy+ay); atomicAdd(&nsum[3*i1+2], cz+az);
            atomicAdd(&nsum[3*i2+0], ax+bx); atomicAdd(&nsum[3*i2+1], ay+by); atomicAdd(&nsum[3*i2+2], az+bz);
            atomicAdd(&deg[i0], 2.0f); atomicAdd(&deg[i1], 2.0f); atomicAdd(&deg[i2], 2.0f);
        }
    }
}

__device__ __forceinline__ float wave_sum(float x) {
    #pragma unroll
    for (int o = 32; o > 0; o >>= 1) x += __shfl_down(x, o, 64);
    return x;
}

__device__ __forceinline__ unsigned long long u64min(unsigned long long a,
                                                     unsigned long long b) {
    return a < b ? a : b;
}

// Group-parallel NN via expanding-box search over the cell-sorted array.
// Box radius r: (2r+1)^2 (z,y) rows, each row's 2r+1 x-cells are one CONTIGUOUS
// span [start[c0], start[c1+1]). Rows round-robin over the 16 lanes; packed
// (d2bits<<32)|idx 16-lane min-reduce == exact first-occurrence argmin.
// Terminate when best <= blo(r)^2 (blo = distance to nearest in-domain box
// face; faces at the domain border have nothing beyond) or box covers grid.
// r=1 succeeds for ~99.98% of queries; r=2 for ~1-1e-10. Rescanning inner
// cells on expansion is harmless (min idempotent). All loop conditions are
// group-uniform -> shuffles safe.
__device__ __forceinline__ unsigned long long group_nn(int lane,
                                                       float px, float py, float pz,
                                                       const float4* __restrict__ S,
                                                       const unsigned* __restrict__ cstart) {
    int cx = cell_of(px), cy = cell_of(py), cz = cell_of(pz);
    unsigned long long best = 0xFFFFFFFFFFFFFFFFULL;
    for (int r = 1; ; ++r) {
        int w = 2 * r + 1;
        int nrows = w * w;
        int x0 = max(cx - r, 0), x1 = min(cx + r, GR - 1);
        unsigned long long lb = 0xFFFFFFFFFFFFFFFFULL;
        for (int k = lane; k < nrows; k += QL) {
            int z = cz + k / w - r, y = cy + k % w - r;
            if (z >= 0 && z < GR && y >= 0 && y < GR) {
                int rowbase = (z * GR + y) * GR;
                unsigned s0 = cstart[rowbase + x0];
                unsigned s1 = cstart[rowbase + x1 + 1];
                for (unsigned t = s0; t < s1; ++t) {
                    float4 q = S[t];
                    float ddx = px - q.x, ddy = py - q.y, ddz = pz - q.z;
                    float d2 = fmaf(ddx, ddx, fmaf(ddy, ddy, ddz*ddz));
                    unsigned long long key =
                        ((unsigned long long)__float_as_uint(d2) << 32) |
                        (unsigned)__float_as_int(q.w);
                    lb = u64min(lb, key);
                }
            }
        }
        best = u64min(best, lb);
        #pragma unroll
        for (int m = 1; m < QL; m <<= 1)
            best = u64min(best, (unsigned long long)__shfl_xor((long long)best, m, 64));
        // covered: box spans the whole grid -> result is exact global min
        bool covered = (cx - r <= 0) & (cx + r >= GR - 1) &
                       (cy - r <= 0) & (cy + r >= GR - 1) &
                       (cz - r <= 0) & (cz + r >= GR - 1);
        if (covered) break;
        float blo = 1.0e30f;
        if (cx - r > 0)      blo = fminf(blo, px - (float)(cx - r) * HCELL);
        if (cx + r < GR - 1) blo = fminf(blo, (float)(cx + r + 1) * HCELL - px);
        if (cy - r > 0)      blo = fminf(blo, py - (float)(cy - r) * HCELL);
        if (cy + r < GR - 1) blo = fminf(blo, (float)(cy + r + 1) * HCELL - py);
        if (cz - r > 0)      blo = fminf(blo, pz - (float)(cz - r) * HCELL);
        if (cz + r < GR - 1) blo = fminf(blo, (float)(cz + r + 1) * HCELL - pz);
        float bd2 = __uint_as_float((unsigned)(best >> 32));
        if (bd2 <= blo * blo) break;   // NaN (no point found) -> false -> expand
    }
    return best;
}

// Dispatch 3: group-parallel NN + per-query terms. NO global atomics/fences:
// block partials go wave->LDS->one plain store to partial[blockIdx].
__global__ __launch_bounds__(256) void query_kernel(const float* __restrict__ relpos,
                                                    const int* __restrict__ label,
                                                    const float4* __restrict__ sortP,
                                                    const float4* __restrict__ sortG,
                                                    const unsigned* __restrict__ startP,
                                                    const unsigned* __restrict__ startG,
                                                    const float* __restrict__ pnn,
                                                    const float* __restrict__ gtn,
                                                    const float* __restrict__ nsum,
                                                    const float* __restrict__ deg,
                                                    float* __restrict__ partial) {
    __shared__ float bsum[6];
    if (threadIdx.x < 6) bsum[threadIdx.x] = 0.0f;
    __syncthreads();
    int lane = threadIdx.x & (QL - 1);
    int group = threadIdx.x >> 4;            // 0..15
    if (blockIdx.x < PRED_QBLOCKS) {
        int qid = blockIdx.x * QPB + group;  // < 8192 (exact)
        float4 P = sortP[qid];
        float px = P.x, py = P.y, pz = P.z;
        unsigned long long key = group_nn(lane, px, py, pz, sortG, startG);

        float r0 = 0.f, r1 = 0.f, r2 = 0.f, r3 = 0.f, r4 = 0.f, r5 = 0.f;
        if (lane == 0) {
            int v = __float_as_int(P.w);               // original pred index
            float dmin = __uint_as_float((unsigned)(key >> 32));
            int nearest = (int)(unsigned)(key & 0xffffffffu);

            // normal consistency (normalize both accumulators on the fly)
            float ax = pnn[3*v], ay = pnn[3*v+1], az = pnn[3*v+2];
            float an = fmaxf(sqrtf(ax*ax + ay*ay + az*az), EPSF);
            float gx = gtn[3*nearest], gy = gtn[3*nearest+1], gz = gtn[3*nearest+2];
            float gn = fmaxf(sqrtf(gx*gx + gy*gy + gz*gz), EPSF);
            float nx = ax/an - gx/gn, ny = ay/an - gy/gn, nz = az/an - gz/gn;
            float sse = nx*nx + ny*ny + nz*nz;

            // laplacian
            float d = fmaxf(deg[v], 1.0f);
            float lx = nsum[3*v]/d - px, ly = nsum[3*v+1]/d - py, lz = nsum[3*v+2]/d - pz;
            float lapn = sqrtf(lx*lx + ly*ly + lz*lz);

            // grid-sample target (nearest, align_corners=True, zeros padding)
            int ix = (int)rintf(px * 95.0f), iy = (int)rintf(py * 95.0f), iz = (int)rintf(pz * 95.0f);
            bool inb = (ix >= 0) & (ix < 96) & (iy >= 0) & (iy < 96) & (iz >= 0) & (iz < 96);
            int ixc = min(max(ix, 0), 95), iyc = min(max(iy, 0), 95), izc = min(max(iz, 0), 95);
            bool pos = inb && (label[(izc*96 + iyc)*96 + ixc] == 1);

            float p = fminf(fmaxf(relpos[v], EPSF), 1.0f - EPSF);
            float om = 1.0f - p;
            float pcnt = 0.0f, sx = 0.0f, sy = 0.0f;
            if (pos) { pcnt = 1.0f; sx = om*om*logf(p); }
            else     { sy = p*p*logf(om); }

            r0 = dmin; r1 = sse; r2 = lapn; r3 = pcnt; r4 = sx; r5 = sy;
        }
        r0 = wave_sum(r0); r1 = wave_sum(r1); r2 = wave_sum(r2);
        r3 = wave_sum(r3); r4 = wave_sum(r4); r5 = wave_sum(r5);
        if ((threadIdx.x & 63) == 0) {       // 4 wave leaders -> LDS atomics (cheap)
            atomicAdd(&bsum[0], r0); atomicAdd(&bsum[1], r1);
            atomicAdd(&bsum[2], r2); atomicAdd(&bsum[3], r3);
            atomicAdd(&bsum[4], r4); atomicAdd(&bsum[5], r5);
        }
        __syncthreads();
        if (threadIdx.x < 6)
            partial[(size_t)blockIdx.x * 8 + threadIdx.x] = bsum[threadIdx.x];
    } else {
        int qid = (blockIdx.x - PRED_QBLOCKS) * QPB + group;  // < 12000 (exact)
        float4 Q = sortG[qid];
        unsigned long long key = group_nn(lane, Q.x, Q.y, Q.z, sortP, startP);
        float val = (lane == 0) ? __uint_as_float((unsigned)(key >> 32)) : 0.0f;
        float r = wave_sum(val);
        if ((threadIdx.x & 63) == 0) atomicAdd(&bsum[0], r);
        __syncthreads();
        if (threadIdx.x == 0)
            partial[(size_t)blockIdx.x * 8] = bsum[0];
    }
}

// Dispatch 4: one block reduces the partial table and writes the final scalar.
__global__ __launch_bounds__(256) void combine_kernel(const float* __restrict__ partial,
                                                      float* __restrict__ out) {
    float s0=0.f, s1=0.f, s2=0.f, s3=0.f, s4=0.f, s5=0.f, s6=0.f;
    for (int r = threadIdx.x; r < FIN_TOTAL; r += 256) {
        const float* p = partial + (size_t)r * 8;
        if (r < PRED_QBLOCKS) {
            s0 += p[0]; s1 += p[1]; s2 += p[2];
            s3 += p[3]; s4 += p[4]; s5 += p[5];
        } else {
            s6 += p[0];
        }
    }
    s0 = wave_sum(s0); s1 = wave_sum(s1); s2 = wave_sum(s2); s3 = wave_sum(s3);
    s4 = wave_sum(s4); s5 = wave_sum(s5); s6 = wave_sum(s6);
    __shared__ float acc[7];
    if (threadIdx.x < 7) acc[threadIdx.x] = 0.0f;
    __syncthreads();
    if ((threadIdx.x & 63) == 0) {
        atomicAdd(&acc[0], s0); atomicAdd(&acc[1], s1); atomicAdd(&acc[2], s2);
        atomicAdd(&acc[3], s3); atomicAdd(&acc[4], s4); atomicAdd(&acc[5], s5);
        atomicAdd(&acc[6], s6);
    }
    __syncthreads();
    if (threadIdx.x == 0) {
        float sum_row = acc[0], sse = acc[1], lap = acc[2];
        float pc = acc[3], SX = acc[4], SY = acc[5], sum_col = acc[6];
        float tot = (float)NP;
        float alpha = (tot - pc) / (tot + EPSF);
        float spatial = (-alpha * SX - (1.0f - alpha) * SY) / (tot + EPSF);
        float distance = sum_row / (float)NP + sum_col / (float)NG;
        float normal = sse / (float)(NP * 3);
        float lapm = lap / (float)NP;
        out[0] = spatial + 1.0f * distance + 0.01f * normal + 0.1f * lapm;
    }
}

extern "C" void kernel_launch(void* const* d_in, const int* in_sizes, int n_in,
                              void* d_out, int out_size, void* d_ws, size_t ws_size,
                              hipStream_t stream) {
    const float* pred   = (const float*)d_in[0];   // [8192,3]
    const float* relpos = (const float*)d_in[1];   // [8192]
    const float* gt     = (const float*)d_in[2];   // [12000,3]
    const int*   pfaces = (const int*)d_in[3];     // [16384,3]
    const int*   gfaces = (const int*)d_in[4];     // [24000,3]
    const int*   label  = (const int*)d_in[5];     // [1,1,96,96,96]
    float* out = (float*)d_out;

    char* ws = (char*)d_ws;
    unsigned* startP  = (unsigned*)(ws + OFF_STARTP);
    unsigned* curP    = (unsigned*)(ws + OFF_CURP);
    unsigned* startG  = (unsigned*)(ws + OFF_STARTG);
    unsigned* curG    = (unsigned*)(ws + OFF_CURG);
    float4*   sortP   = (float4*)(ws + OFF_SORTP);
    float4*   sortG   = (float4*)(ws + OFF_SORTG);
    float*    gtn     = (float*)(ws + OFF_GTN);
    float*    pnn     = (float*)(ws + OFF_PNN);
    float*    nsum    = (float*)(ws + OFF_NSUM);
    float*    deg     = (float*)(ws + OFF_DEG);
    float*    partial = (float*)(ws + OFF_PART);

    // d1: build histograms+scans (blocks 0,1) || zero accumulators (blocks 2..)
    int zero_blocks = (N_ZERO + 1023) / 1024;      // 92
    hipLaunchKernelGGL(build_kernel, dim3(2 + zero_blocks), dim3(1024), 0, stream,
                       pred, gt, startP, curP, startG, curG, gtn);
    // d2: scatter into cell order + face/laplacian scatter
    hipLaunchKernelGGL(scatter_faces_kernel, dim3(SCAT_BLOCKS + FACE_BLOCKS), dim3(256), 0, stream,
                       pred, pfaces, gt, gfaces, curP, curG, sortP, sortG,
                       gtn, pnn, nsum, deg);
    // d3: group-parallel grid-NN + per-query terms -> per-block partials
    hipLaunchKernelGGL(query_kernel, dim3(FIN_TOTAL), dim3(256), 0, stream,
                       relpos, label, sortP, sortG, startP, startG,
                       pnn, gtn, nsum, deg, partial);
    // d4: reduce partials + final combine
    hipLaunchKernelGGL(combine_kernel, dim3(1), dim3(256), 0, stream, partial, out);
}